// Round 1
// baseline (80.821 us; speedup 1.0000x reference)
//
#include <hip/hip_runtime.h>
#include <hip/hip_bf16.h>

// SoftDP: soft value-iteration backward over H, then softmax over K.
// E: [B=2048, H=64, K=512] f32.  out: [B, K] f32.
// Recurrence (per b, t = H-1 .. 0):
//   m = max_k V[k]; s = sum_k exp(V[k]-m)
//   V[k] <- -E[b,t,k] + m + log(exp(-kappa)*s + exp(V[k]-m))
// We renormalize (drop the +m) each step: softmax output is shift-invariant
// and the recurrence is shift-equivariant.

#define BB 2048
#define HH 64
#define KK 512
#define THREADS 128  // KK/4 threads, float4 per thread

__device__ __forceinline__ float wave_max(float v) {
#pragma unroll
    for (int off = 32; off >= 1; off >>= 1) v = fmaxf(v, __shfl_xor(v, off));
    return v;
}
__device__ __forceinline__ float wave_sum(float v) {
#pragma unroll
    for (int off = 32; off >= 1; off >>= 1) v += __shfl_xor(v, off);
    return v;
}

__global__ __launch_bounds__(THREADS) void softdp_kernel(
        const float* __restrict__ E, float* __restrict__ out) {
    const int b    = blockIdx.x;
    const int tid  = threadIdx.x;
    const int lane = tid & 63;
    const int wid  = tid >> 6;  // 0 or 1

    __shared__ float lds_m[2];
    __shared__ float lds_s[2];

    const float4* Erow = reinterpret_cast<const float4*>(E) + (size_t)b * (HH * KK / 4);
    float4*       Orow = reinterpret_cast<float4*>(out)     + (size_t)b * (KK / 4);

    const float c = 0.6065306597126334f;  // exp(-kappa), kappa = 0.5

    float V[4] = {0.f, 0.f, 0.f, 0.f};

    // prefetch t = H-1
    float4 e = Erow[(HH - 1) * (KK / 4) + tid];

    for (int t = HH - 1; t >= 0; --t) {
        // issue next load early so HBM latency hides under the reductions
        const int tn = (t > 0) ? (t - 1) : 0;
        float4 e_next = Erow[tn * (KK / 4) + tid];

        // ---- block max of V ----
        float m = fmaxf(fmaxf(V[0], V[1]), fmaxf(V[2], V[3]));
        m = wave_max(m);
        if (lane == 0) lds_m[wid] = m;
        __syncthreads();
        m = fmaxf(lds_m[0], lds_m[1]);

        // ---- block sum of exp(V - m) ----
        float x0 = expf(V[0] - m);
        float x1 = expf(V[1] - m);
        float x2 = expf(V[2] - m);
        float x3 = expf(V[3] - m);
        float s = wave_sum((x0 + x1) + (x2 + x3));
        if (lane == 0) lds_s[wid] = s;
        __syncthreads();
        s = lds_s[0] + lds_s[1];

        // ---- update (renormalized: m dropped) ----
        const float cs = c * s;
        V[0] = -e.x + logf(cs + x0);
        V[1] = -e.y + logf(cs + x1);
        V[2] = -e.z + logf(cs + x2);
        V[3] = -e.w + logf(cs + x3);

        e = e_next;
    }

    // ---- final softmax over K ----
    float m = fmaxf(fmaxf(V[0], V[1]), fmaxf(V[2], V[3]));
    m = wave_max(m);
    if (lane == 0) lds_m[wid] = m;
    __syncthreads();
    m = fmaxf(lds_m[0], lds_m[1]);

    float x0 = expf(V[0] - m);
    float x1 = expf(V[1] - m);
    float x2 = expf(V[2] - m);
    float x3 = expf(V[3] - m);
    float s = wave_sum((x0 + x1) + (x2 + x3));
    if (lane == 0) lds_s[wid] = s;
    __syncthreads();
    s = lds_s[0] + lds_s[1];

    const float inv = 1.0f / s;
    float4 o;
    o.x = x0 * inv;
    o.y = x1 * inv;
    o.z = x2 * inv;
    o.w = x3 * inv;
    Orow[tid] = o;
}

extern "C" void kernel_launch(void* const* d_in, const int* in_sizes, int n_in,
                              void* d_out, int out_size, void* d_ws, size_t ws_size,
                              hipStream_t stream) {
    const float* E = (const float*)d_in[0];
    float* out = (float*)d_out;
    softdp_kernel<<<dim3(BB), dim3(THREADS), 0, stream>>>(E, out);
}

// Round 2
// 63.918 us; speedup vs baseline: 1.2644x; 1.2644x over previous
//
#include <hip/hip_runtime.h>
#include <hip/hip_bf16.h>

// SoftDP: soft value-iteration backward over H, then softmax over K.
// E: [B=2048, H=64, K=512] f32.  out: [B, K] f32.
// Per b, t = H-1 .. 0 (with per-step renormalization by m = max_k V):
//   x_k = exp(V_k - m); s = sum_k x_k
//   V_k <- -E[b,t,k] + log(exp(-kappa)*s + x_k)     (shift-equivariant)
// Final: softmax(V) over K (shift-invariant, so dropped +m terms cancel).
//
// R2 structure: ONE wave per row (64 lanes x 8 elems = K=512).
//   - reductions are pure __shfl_xor: no barriers, no LDS
//   - prefetch depth 2 (E[t-1], E[t-2] in registers) to hide HBM latency
//     at 8 waves/CU occupancy
//   - native __expf/__logf (args bounded: |V-m| <= ~20, cs+x >= 0.6)

#define BB 2048
#define HH 64
#define KK 512

__device__ __forceinline__ float wave_max(float v) {
#pragma unroll
    for (int off = 32; off >= 1; off >>= 1) v = fmaxf(v, __shfl_xor(v, off));
    return v;
}
__device__ __forceinline__ float wave_sum(float v) {
#pragma unroll
    for (int off = 32; off >= 1; off >>= 1) v += __shfl_xor(v, off);
    return v;
}

__global__ __launch_bounds__(64) void softdp_kernel(
        const float* __restrict__ E, float* __restrict__ out) {
    const int b    = blockIdx.x;
    const int lane = threadIdx.x;

    // lane owns elements [8*lane, 8*lane+8) = float4 indices 2*lane, 2*lane+1
    const float4* __restrict__ Erow =
        reinterpret_cast<const float4*>(E) + (size_t)b * (HH * KK / 4) + 2 * lane;
    float4* __restrict__ Orow =
        reinterpret_cast<float4*>(out) + (size_t)b * (KK / 4) + 2 * lane;

    const float c = 0.6065306597126334f;  // exp(-kappa), kappa = 0.5

    float V[8] = {0.f, 0.f, 0.f, 0.f, 0.f, 0.f, 0.f, 0.f};

    // prefetch t = H-1 and t = H-2
    float4 eA0 = Erow[(HH - 1) * (KK / 4)];
    float4 eA1 = Erow[(HH - 1) * (KK / 4) + 1];
    float4 eB0 = Erow[(HH - 2) * (KK / 4)];
    float4 eB1 = Erow[(HH - 2) * (KK / 4) + 1];

    for (int t = HH - 1; t >= 0; --t) {
        // issue load of E[t-2] (clamped; redundant tail loads hit L2)
        const int tn = (t >= 2) ? (t - 2) : 0;
        float4 eC0 = Erow[tn * (KK / 4)];
        float4 eC1 = Erow[tn * (KK / 4) + 1];

        // ---- wave max of V (local tree + 6-level shfl) ----
        float m01 = fmaxf(V[0], V[1]), m23 = fmaxf(V[2], V[3]);
        float m45 = fmaxf(V[4], V[5]), m67 = fmaxf(V[6], V[7]);
        float m = fmaxf(fmaxf(m01, m23), fmaxf(m45, m67));
        m = wave_max(m);

        // ---- x = exp(V - m), wave sum ----
        float x0 = __expf(V[0] - m), x1 = __expf(V[1] - m);
        float x2 = __expf(V[2] - m), x3 = __expf(V[3] - m);
        float x4 = __expf(V[4] - m), x5 = __expf(V[5] - m);
        float x6 = __expf(V[6] - m), x7 = __expf(V[7] - m);
        float s = ((x0 + x1) + (x2 + x3)) + ((x4 + x5) + (x6 + x7));
        s = wave_sum(s);

        // ---- update (renormalized: +m dropped) ----
        const float cs = c * s;
        V[0] = -eA0.x + __logf(cs + x0);
        V[1] = -eA0.y + __logf(cs + x1);
        V[2] = -eA0.z + __logf(cs + x2);
        V[3] = -eA0.w + __logf(cs + x3);
        V[4] = -eA1.x + __logf(cs + x4);
        V[5] = -eA1.y + __logf(cs + x5);
        V[6] = -eA1.z + __logf(cs + x6);
        V[7] = -eA1.w + __logf(cs + x7);

        // rotate prefetch pipeline
        eA0 = eB0; eA1 = eB1;
        eB0 = eC0; eB1 = eC1;
    }

    // ---- final softmax over K ----
    float m01 = fmaxf(V[0], V[1]), m23 = fmaxf(V[2], V[3]);
    float m45 = fmaxf(V[4], V[5]), m67 = fmaxf(V[6], V[7]);
    float m = fmaxf(fmaxf(m01, m23), fmaxf(m45, m67));
    m = wave_max(m);

    float x0 = __expf(V[0] - m), x1 = __expf(V[1] - m);
    float x2 = __expf(V[2] - m), x3 = __expf(V[3] - m);
    float x4 = __expf(V[4] - m), x5 = __expf(V[5] - m);
    float x6 = __expf(V[6] - m), x7 = __expf(V[7] - m);
    float s = ((x0 + x1) + (x2 + x3)) + ((x4 + x5) + (x6 + x7));
    s = wave_sum(s);

    const float inv = 1.0f / s;
    float4 o0, o1;
    o0.x = x0 * inv; o0.y = x1 * inv; o0.z = x2 * inv; o0.w = x3 * inv;
    o1.x = x4 * inv; o1.y = x5 * inv; o1.z = x6 * inv; o1.w = x7 * inv;
    Orow[0] = o0;
    Orow[1] = o1;
}

extern "C" void kernel_launch(void* const* d_in, const int* in_sizes, int n_in,
                              void* d_out, int out_size, void* d_ws, size_t ws_size,
                              hipStream_t stream) {
    const float* E = (const float*)d_in[0];
    float* out = (float*)d_out;
    softdp_kernel<<<dim3(BB), dim3(64), 0, stream>>>(E, out);
}

// Round 3
// 49.629 us; speedup vs baseline: 1.6285x; 1.2879x over previous
//
#include <hip/hip_runtime.h>
#include <hip/hip_bf16.h>

// SoftDP: soft value-iteration backward over H, then softmax over K.
// E: [B=2048, H=64, K=512] f32.  out: [B, K] f32.
//
// R3 algebra: renormalize each step by log(c*S) instead of max(V):
//   X_k = exp(V_k);  S = sum_k X_k
//   V_k <- -E[b,t,k] + log(1 + X_k/(c*S)),   c = exp(-kappa)
// Proof of boundedness: X_k/(c*S) <= 1/c (since S >= X_k), so
//   V in [-max|e|, -e + log(1+1/c)] subset of ~[-6.5, 6.5] -> exp(V) <= 665,
//   S <= 3.4e5: no overflow, no max-reduction needed (also not for the final
//   softmax). Softmax is shift-invariant so the dropped log(c*S) shifts cancel.
//
// Structure: one wave per row (64 lanes x 8 elems), shfl-only sum reduce,
// prefetch depth 3, native exp/log/rcp.

#define BB 2048
#define HH 64
#define KK 512

__device__ __forceinline__ float wave_sum(float v) {
#pragma unroll
    for (int off = 32; off >= 1; off >>= 1) v += __shfl_xor(v, off);
    return v;
}

__global__ __launch_bounds__(64) void softdp_kernel(
        const float* __restrict__ E, float* __restrict__ out) {
    const int b    = blockIdx.x;
    const int lane = threadIdx.x;

    const float4* __restrict__ Erow =
        reinterpret_cast<const float4*>(E) + (size_t)b * (HH * KK / 4) + 2 * lane;
    float4* __restrict__ Orow =
        reinterpret_cast<float4*>(out) + (size_t)b * (KK / 4) + 2 * lane;

    const float c = 0.6065306597126334f;  // exp(-kappa), kappa = 0.5

    float V[8] = {0.f, 0.f, 0.f, 0.f, 0.f, 0.f, 0.f, 0.f};

    // prefetch pipeline: A = E[t], B = E[t-1], C = E[t-2]
    float4 eA0 = Erow[(HH - 1) * (KK / 4)], eA1 = Erow[(HH - 1) * (KK / 4) + 1];
    float4 eB0 = Erow[(HH - 2) * (KK / 4)], eB1 = Erow[(HH - 2) * (KK / 4) + 1];
    float4 eC0 = Erow[(HH - 3) * (KK / 4)], eC1 = Erow[(HH - 3) * (KK / 4) + 1];

    for (int t = HH - 1; t >= 0; --t) {
        // issue load of E[t-3] (clamped; tail re-loads hit L1/L2)
        const int tn = (t >= 3) ? (t - 3) : 0;
        float4 eD0 = Erow[tn * (KK / 4)];
        float4 eD1 = Erow[tn * (KK / 4) + 1];

        // ---- X = exp(V), wave sum (no max shift needed: V bounded) ----
        float x0 = __expf(V[0]), x1 = __expf(V[1]);
        float x2 = __expf(V[2]), x3 = __expf(V[3]);
        float x4 = __expf(V[4]), x5 = __expf(V[5]);
        float x6 = __expf(V[6]), x7 = __expf(V[7]);
        float s = ((x0 + x1) + (x2 + x3)) + ((x4 + x5) + (x6 + x7));
        s = wave_sum(s);

        // ---- update, renormalized by log(c*s) ----
        const float r = __builtin_amdgcn_rcpf(c * s);
        V[0] = -eA0.x + __logf(fmaf(x0, r, 1.0f));
        V[1] = -eA0.y + __logf(fmaf(x1, r, 1.0f));
        V[2] = -eA0.z + __logf(fmaf(x2, r, 1.0f));
        V[3] = -eA0.w + __logf(fmaf(x3, r, 1.0f));
        V[4] = -eA1.x + __logf(fmaf(x4, r, 1.0f));
        V[5] = -eA1.y + __logf(fmaf(x5, r, 1.0f));
        V[6] = -eA1.z + __logf(fmaf(x6, r, 1.0f));
        V[7] = -eA1.w + __logf(fmaf(x7, r, 1.0f));

        // rotate prefetch pipeline
        eA0 = eB0; eA1 = eB1;
        eB0 = eC0; eB1 = eC1;
        eC0 = eD0; eC1 = eD1;
    }

    // ---- final softmax over K (V bounded: no max shift) ----
    float x0 = __expf(V[0]), x1 = __expf(V[1]);
    float x2 = __expf(V[2]), x3 = __expf(V[3]);
    float x4 = __expf(V[4]), x5 = __expf(V[5]);
    float x6 = __expf(V[6]), x7 = __expf(V[7]);
    float s = ((x0 + x1) + (x2 + x3)) + ((x4 + x5) + (x6 + x7));
    s = wave_sum(s);

    const float inv = __builtin_amdgcn_rcpf(s);
    float4 o0, o1;
    o0.x = x0 * inv; o0.y = x1 * inv; o0.z = x2 * inv; o0.w = x3 * inv;
    o1.x = x4 * inv; o1.y = x5 * inv; o1.z = x6 * inv; o1.w = x7 * inv;
    Orow[0] = o0;
    Orow[1] = o1;
}

extern "C" void kernel_launch(void* const* d_in, const int* in_sizes, int n_in,
                              void* d_out, int out_size, void* d_ws, size_t ws_size,
                              hipStream_t stream) {
    const float* E = (const float*)d_in[0];
    float* out = (float*)d_out;
    softdp_kernel<<<dim3(BB), dim3(64), 0, stream>>>(E, out);
}

// Round 5
// 46.688 us; speedup vs baseline: 1.7311x; 1.0630x over previous
//
#include <hip/hip_runtime.h>
#include <hip/hip_bf16.h>

// SoftDP: soft value-iteration backward over H, then softmax over K.
// E: [B=2048, H=64, K=512] f32.  out: [B, K] f32.
//
// Algebra (R3): renormalize each step by log(c*S) instead of max(V):
//   X_k = exp(V_k);  S = sum_k X_k
//   V_k <- -E[b,t,k] + log(1 + X_k/(c*S)),   c = exp(-kappa)
// X_k/(c*S) <= 1/c, so V stays in ~[-6.5, 6.5]: no overflow, no max pass.
// Softmax is shift-invariant so the dropped log(c*S) shifts cancel.
//
// R4/R5: replace the 6-level ds_swizzle shuffle reduction (6 dependent
// LDS-latency hops, ~400-700 cyc) with:
//   xor1,2   : DPP quad_perm   (VALU latency)
//   xor4     : DPP row_half_mirror (== xor4 once quads are uniform)
//   xor8     : DPP row_mirror      (== xor8 once 8-groups are uniform)
//   xor16    : ds_swizzle (the ONLY LDS hop; swizzle is 32-lane-scoped)
//   xor32    : v_permlane32_swap: with a==b==x, new_a+new_b = x[l]+x[l^32]
// One wave per row (64 lanes x 8 elems), prefetch depth 3, native exp/log.

#define BB 2048
#define HH 64
#define KK 512

template <int CTRL>
__device__ __forceinline__ float dpp_add(float v) {
    int s = __builtin_amdgcn_update_dpp(__float_as_int(v), __float_as_int(v),
                                        CTRL, 0xf, 0xf, false);
    return v + __int_as_float(s);
}

__device__ __forceinline__ float wave_sum_fast(float p) {
    // xor16 first (the single LDS-latency hop)
    float t = __int_as_float(__builtin_amdgcn_ds_swizzle(__float_as_int(p), 0x401F));
    float s = p + t;
    s = dpp_add<0xB1>(s);    // quad_perm [1,0,3,2]  : xor1
    s = dpp_add<0x4E>(s);    // quad_perm [2,3,0,1]  : xor2
    s = dpp_add<0x141>(s);   // row_half_mirror      : xor4 (quads uniform)
    s = dpp_add<0x140>(s);   // row_mirror           : xor8 (8-groups uniform)
    auto pr = __builtin_amdgcn_permlane32_swap(__float_as_int(s),
                                               __float_as_int(s), false, false);
    return __int_as_float(pr[0]) + __int_as_float(pr[1]);  // + xor32
}

__global__ __launch_bounds__(64) void softdp_kernel(
        const float* __restrict__ E, float* __restrict__ out) {
    const int b    = blockIdx.x;
    const int lane = threadIdx.x;

    const float4* __restrict__ Erow =
        reinterpret_cast<const float4*>(E) + (size_t)b * (HH * KK / 4) + 2 * lane;
    float4* __restrict__ Orow =
        reinterpret_cast<float4*>(out) + (size_t)b * (KK / 4) + 2 * lane;

    const float c = 0.6065306597126334f;  // exp(-kappa), kappa = 0.5

    float V[8] = {0.f, 0.f, 0.f, 0.f, 0.f, 0.f, 0.f, 0.f};

    // prefetch pipeline: A = E[t], B = E[t-1], C = E[t-2]
    float4 eA0 = Erow[(HH - 1) * (KK / 4)], eA1 = Erow[(HH - 1) * (KK / 4) + 1];
    float4 eB0 = Erow[(HH - 2) * (KK / 4)], eB1 = Erow[(HH - 2) * (KK / 4) + 1];
    float4 eC0 = Erow[(HH - 3) * (KK / 4)], eC1 = Erow[(HH - 3) * (KK / 4) + 1];

    for (int t = HH - 1; t >= 0; --t) {
        // issue load of E[t-3] (clamped; tail re-loads hit L1/L2)
        const int tn = (t >= 3) ? (t - 3) : 0;
        float4 eD0 = Erow[tn * (KK / 4)];
        float4 eD1 = Erow[tn * (KK / 4) + 1];

        // ---- X = exp(V), wave sum (V bounded: no max shift) ----
        float x0 = __expf(V[0]), x1 = __expf(V[1]);
        float x2 = __expf(V[2]), x3 = __expf(V[3]);
        float x4 = __expf(V[4]), x5 = __expf(V[5]);
        float x6 = __expf(V[6]), x7 = __expf(V[7]);
        float p = ((x0 + x1) + (x2 + x3)) + ((x4 + x5) + (x6 + x7));
        float s = wave_sum_fast(p);

        // ---- update, renormalized by log(c*s) ----
        const float r = __builtin_amdgcn_rcpf(c * s);
        V[0] = -eA0.x + __logf(fmaf(x0, r, 1.0f));
        V[1] = -eA0.y + __logf(fmaf(x1, r, 1.0f));
        V[2] = -eA0.z + __logf(fmaf(x2, r, 1.0f));
        V[3] = -eA0.w + __logf(fmaf(x3, r, 1.0f));
        V[4] = -eA1.x + __logf(fmaf(x4, r, 1.0f));
        V[5] = -eA1.y + __logf(fmaf(x5, r, 1.0f));
        V[6] = -eA1.z + __logf(fmaf(x6, r, 1.0f));
        V[7] = -eA1.w + __logf(fmaf(x7, r, 1.0f));

        // rotate prefetch pipeline
        eA0 = eB0; eA1 = eB1;
        eB0 = eC0; eB1 = eC1;
        eC0 = eD0; eC1 = eD1;
    }

    // ---- final softmax over K ----
    float x0 = __expf(V[0]), x1 = __expf(V[1]);
    float x2 = __expf(V[2]), x3 = __expf(V[3]);
    float x4 = __expf(V[4]), x5 = __expf(V[5]);
    float x6 = __expf(V[6]), x7 = __expf(V[7]);
    float p = ((x0 + x1) + (x2 + x3)) + ((x4 + x5) + (x6 + x7));
    float s = wave_sum_fast(p);

    const float inv = __builtin_amdgcn_rcpf(s);
    float4 o0, o1;
    o0.x = x0 * inv; o0.y = x1 * inv; o0.z = x2 * inv; o0.w = x3 * inv;
    o1.x = x4 * inv; o1.y = x5 * inv; o1.z = x6 * inv; o1.w = x7 * inv;
    Orow[0] = o0;
    Orow[1] = o1;
}

extern "C" void kernel_launch(void* const* d_in, const int* in_sizes, int n_in,
                              void* d_out, int out_size, void* d_ws, size_t ws_size,
                              hipStream_t stream) {
    const float* E = (const float*)d_in[0];
    float* out = (float*)d_out;
    softdp_kernel<<<dim3(BB), dim3(64), 0, stream>>>(E, out);
}